// Round 18
// baseline (211.514 us; speedup 1.0000x reference)
//
#include <hip/hip_runtime.h>

// QuantizerEMA (B,H,W,D,K)=(32,32,32,64,1024), N=32768. fp32 in / fp32 out.
// Output float32 chunks: QV[B,D,H,W] (N*64), IDX (N), loss, EMB[K,64], CL[K],
// EMA[K,64]. R18 = R17 + packed-fp32 inner loop: acc as float2 pairs so the
// contraction lowers to v_pk_fma_f32 (VOP3P; per-component IEEE fma ==
// v_fma_f32 bitwise, each acc chain still sequential d=0..63 -> argmin
// bitwise as R9-R17). Everything else identical to R17 (94us k_main, no
// spill, 5.0e6 conflicts).

typedef unsigned short u16;
typedef u16 us8 __attribute__((ext_vector_type(8)));
typedef float f4 __attribute__((ext_vector_type(4)));
typedef float f2 __attribute__((ext_vector_type(2)));

#define WS_FZ    0
#define WS_FE    1
#define WS_FCS   2
#define WS_FEMA  3
#define WS_LOSS  4

__device__ __forceinline__ float b2f(u16 u) {
    union { unsigned int i; float f; } x; x.i = ((unsigned int)u) << 16; return x.f;
}
__device__ __forceinline__ int swzE(int d, int c) {
    return d * 64 + (c ^ ((((d) >> 2) & 7) << 2));
}
__device__ __forceinline__ int swzZ(int d, int c) {
    int cb = (c >> 2) ^ (c >> 5);
    int cc = ((cb & 31) << 2) | (c & 3);
    return d * 128 + (cc ^ ((((d) >> 2) & 7) << 2));
}

// ---------- kernel 1: dtype detect + e^2 table ----------
__global__ __launch_bounds__(256) void k_init(
    const u16* z, const u16* e, const u16* cs, const u16* ema,
    float* __restrict__ ws, float* __restrict__ esqp, int K)
{
    __shared__ int flg[4];
    const int w = threadIdx.x >> 6, l = threadIdx.x & 63;
    const u16* p = (w == 0) ? z : (w == 1) ? e : (w == 2) ? cs : ema;
    int cnt = 0;
    #pragma unroll
    for (int t = 0; t < 4; ++t) {
        unsigned hb = (p[(l * 4 + t) * 2] >> 8) & 0x7F;
        cnt += (hb >= 0x3A && hb <= 0x41) ? 1 : 0;
    }
    #pragma unroll
    for (int off = 32; off; off >>= 1) cnt += __shfl_down(cnt, off);
    if (l == 0) flg[w] = (cnt < 128) ? 1 : 0;
    __syncthreads();
    if (blockIdx.x == 0) {
        if (threadIdx.x < 4) ((int*)ws)[threadIdx.x] = flg[threadIdx.x];
        if (threadIdx.x == 4) ws[WS_LOSS] = 0.0f;
    }
    const int fe = flg[1];
    const int code = blockIdx.x * 256 + threadIdx.x;
    if (code < K) {
        float r[8];
        if (fe) {
            const float* ep = (const float*)e + (size_t)code * 64;
            #pragma unroll
            for (int j = 0; j < 8; ++j) { float v = ep[j]; float p2 = v * v;
                asm volatile("" : "+v"(p2)); r[j] = p2; }
            #pragma unroll
            for (int t = 1; t < 8; ++t)
                #pragma unroll
                for (int j = 0; j < 8; ++j) { float v = ep[8 * t + j]; float p2 = v * v;
                    asm volatile("" : "+v"(p2)); r[j] += p2; }
        } else {
            const u16* ep = e + (size_t)code * 64;
            #pragma unroll
            for (int j = 0; j < 8; ++j) { float v = b2f(ep[j]); float p2 = v * v;
                asm volatile("" : "+v"(p2)); r[j] = p2; }
            #pragma unroll
            for (int t = 1; t < 8; ++t)
                #pragma unroll
                for (int j = 0; j < 8; ++j) { float v = b2f(ep[8 * t + j]); float p2 = v * v;
                    asm volatile("" : "+v"(p2)); r[j] += p2; }
        }
        esqp[code] = ((r[0] + r[1]) + (r[2] + r[3])) + ((r[4] + r[5]) + (r[6] + r[7]));
    }
}

// ---------- kernel 2: distances + argmin + QV/loss epilogue ----------
__global__ __launch_bounds__(512, 2) void k_main(
    const u16* __restrict__ z, const u16* __restrict__ e,
    const float* __restrict__ esqp,
    float* __restrict__ ws, float* __restrict__ out,
    int K, int offIdx, long long outSize)
{
    __shared__ __align__(16) float z_t[64 * 128];       // 32 KB, swzZ
    __shared__ __align__(16) float e_t[4 * 64 * 64];    // 64 KB, swzE per group
    __shared__ float esq_l[2048];                       // 8 KB (K <= 2048)
    __shared__ float z2_l[128];
    __shared__ int   idx_l[128];

    const int tid = threadIdx.x;
    const int cg  = tid >> 7;
    const int lt  = tid & 127;
    const int mtg = lt & 15;
    const int ktg = lt >> 4;
    const int pbase = blockIdx.x * 128;
    const int* wsi = (const int*)ws;
    const int fz = wsi[WS_FZ];
    const int fe = wsi[WS_FE];
    const int kchunks = K >> 6;
    const int h = kchunks >> 2;

    for (int i = tid; i < K; i += 512) esq_l[i] = esqp[i];

    if (fz) {
        const f4* z4 = (const f4*)((const float*)z + (size_t)pbase * 64);
        for (int i = tid; i < 2048; i += 512) {
            f4 v = z4[i];
            int m = i >> 4, d4 = (i & 15) * 4;
            z_t[swzZ(d4 + 0, m)] = v[0];
            z_t[swzZ(d4 + 1, m)] = v[1];
            z_t[swzZ(d4 + 2, m)] = v[2];
            z_t[swzZ(d4 + 3, m)] = v[3];
        }
    } else {
        const us8* z8 = (const us8*)(z + (size_t)pbase * 64);
        for (int i = tid; i < 1024; i += 512) {
            us8 v = z8[i];
            int m = i >> 3, d8 = (i & 7) * 8;
            #pragma unroll
            for (int t = 0; t < 8; ++t) z_t[swzZ(d8 + t, m)] = b2f(v[t]);
        }
    }
    __syncthreads();
    if (tid < 128) {   // ||z||^2, np pairwise-8 order, anti-FMA barriers
        float r[8];
        #pragma unroll
        for (int j = 0; j < 8; ++j) {
            float v = z_t[swzZ(j, tid)]; float p = v * v;
            asm volatile("" : "+v"(p)); r[j] = p;
        }
        #pragma unroll
        for (int t = 1; t < 8; ++t)
            #pragma unroll
            for (int j = 0; j < 8; ++j) {
                float v = z_t[swzZ(8 * t + j, tid)]; float p = v * v;
                asm volatile("" : "+v"(p)); r[j] += p;
            }
        z2_l[tid] = ((r[0] + r[1]) + (r[2] + r[3])) + ((r[4] + r[5]) + (r[6] + r[7]));
    }

    float bestd[8] = {INFINITY, INFINITY, INFINITY, INFINITY,
                      INFINITY, INFINITY, INFINITY, INFINITY};
    int   besti[8] = {0, 0, 0, 0, 0, 0, 0, 0};
    float* et = e_t + cg * 4096;

    f4  fb[8];
    us8 hb[4];
    {
        int kc0 = cg * h;
        if (fe) {
            const f4* e4 = (const f4*)((const float*)e + (size_t)kc0 * 4096);
            #pragma unroll
            for (int t = 0; t < 8; ++t) fb[t] = e4[lt + 128 * t];
        } else {
            const us8* e8 = (const us8*)(e + (size_t)kc0 * 4096);
            #pragma unroll
            for (int t = 0; t < 4; ++t) hb[t] = e8[lt + 128 * t];
        }
    }

    for (int c = 0; c < h; ++c) {
        const int kc = cg * h + c;
        if (fe) {
            #pragma unroll
            for (int t = 0; t < 8; ++t) {
                int i = lt + 128 * t;
                int kl = i >> 4, d4 = (i & 15) * 4;
                et[swzE(d4 + 0, kl)] = fb[t][0];
                et[swzE(d4 + 1, kl)] = fb[t][1];
                et[swzE(d4 + 2, kl)] = fb[t][2];
                et[swzE(d4 + 3, kl)] = fb[t][3];
            }
        } else {
            #pragma unroll
            for (int t = 0; t < 4; ++t) {
                int i = lt + 128 * t;
                int kl = i >> 3, d8 = (i & 7) * 8;
                #pragma unroll
                for (int s = 0; s < 8; ++s) et[swzE(d8 + s, kl)] = b2f(hb[t][s]);
            }
        }
        if (c + 1 < h) {
            if (fe) {
                const f4* e4 = (const f4*)((const float*)e + (size_t)(kc + 1) * 4096);
                #pragma unroll
                for (int t = 0; t < 8; ++t) fb[t] = e4[lt + 128 * t];
            } else {
                const us8* e8 = (const us8*)(e + (size_t)(kc + 1) * 4096);
                #pragma unroll
                for (int t = 0; t < 4; ++t) hb[t] = e8[lt + 128 * t];
            }
        }
        __syncthreads();

        // acc as float2 pairs -> v_pk_fma_f32; component chains stay
        // sequential d=0..63 (bitwise == R17's scalar v_fma_f32 chains)
        f2 acc[8][4] = {};
        for (int d0 = 0; d0 < 64; d0 += 4) {
            f4 za[4], zb[4], ea[4], eb[4];
            #pragma unroll
            for (int j = 0; j < 4; ++j) {
                int d = d0 + j;
                za[j] = *(const f4*)&z_t[swzZ(d, mtg * 8)];
                zb[j] = *(const f4*)&z_t[swzZ(d, mtg * 8 + 4)];
                ea[j] = *(const f4*)&et[swzE(d, ktg * 8)];
                eb[j] = *(const f4*)&et[swzE(d, ktg * 8 + 4)];
            }
            #pragma unroll
            for (int j = 0; j < 4; ++j) {
                f2 e0 = __builtin_shufflevector(ea[j], ea[j], 0, 1);
                f2 e1 = __builtin_shufflevector(ea[j], ea[j], 2, 3);
                f2 e2 = __builtin_shufflevector(eb[j], eb[j], 0, 1);
                f2 e3 = __builtin_shufflevector(eb[j], eb[j], 2, 3);
                #pragma unroll
                for (int a = 0; a < 4; ++a) {
                    f2 zda = (f2){za[j][a], za[j][a]};
                    f2 zdb = (f2){zb[j][a], zb[j][a]};
                    acc[a][0]     += zda * e0;
                    acc[a][1]     += zda * e1;
                    acc[a][2]     += zda * e2;
                    acc[a][3]     += zda * e3;
                    acc[a + 4][0] += zdb * e0;
                    acc[a + 4][1] += zdb * e1;
                    acc[a + 4][2] += zdb * e2;
                    acc[a + 4][3] += zdb * e3;
                }
            }
        }
        __syncthreads();

        #pragma unroll
        for (int a = 0; a < 8; ++a) {
            float z2 = z2_l[mtg * 8 + a];
            #pragma unroll
            for (int b = 0; b < 8; ++b) {
                float e2v = esq_l[kc * 64 + ktg * 8 + b];
                float dist = (z2 + e2v) - 2.0f * acc[a][b >> 1][b & 1];
                int kg = kc * 64 + ktg * 8 + b;
                if (dist < bestd[a]) { bestd[a] = dist; besti[a] = kg; }  // first-wins
            }
        }
    }

    // ---- argmin merge: 32 slots/point, stride 33, overlay e_t ----
    float* red_d = e_t;
    int*   red_i = (int*)(e_t + 4224);
    #pragma unroll
    for (int a = 0; a < 8; ++a) {
        red_d[(mtg * 8 + a) * 33 + (cg * 8 + ktg)] = bestd[a];
        red_i[(mtg * 8 + a) * 33 + (cg * 8 + ktg)] = besti[a];
    }
    __syncthreads();

    if (tid < 128) {
        float bd = red_d[tid * 33]; int bi = red_i[tid * 33];
        #pragma unroll
        for (int t = 1; t < 32; ++t) {
            float dv = red_d[tid * 33 + t]; int iv = red_i[tid * 33 + t];
            if (dv < bd || (dv == bd && iv < bi)) { bd = dv; bi = iv; }
        }
        idx_l[tid] = bi;
        long long oi = (long long)offIdx + pbase + tid;
        if (oi < outSize) out[oi] = (float)bi;
    }
    __syncthreads();

    // ---- epilogue: QV transposed store + loss ----
    const int m = tid & 127;
    const int w = tid >> 7;
    const int p = pbase + m;
    const int b = p >> 10;
    const int hw = p & 1023;
    const int kidx = idx_l[m];
    float lsum = 0.f;
    #pragma unroll
    for (int dd = 0; dd < 16; ++dd) {
        int d = w + 4 * dd;
        float zv = z_t[swzZ(d, m)];
        float q  = fe ? ((const float*)e)[(size_t)kidx * 64 + d]
                      : b2f(e[(size_t)kidx * 64 + d]);
        float df = zv - q;
        lsum += df * df;
        float qs = zv + (q - zv);
        long long qi = (long long)b * 65536 + d * 1024 + hw;
        if (qi < outSize) out[qi] = qs;
    }
    #pragma unroll
    for (int off = 32; off; off >>= 1) lsum += __shfl_down(lsum, off);
    if ((tid & 63) == 0) atomicAdd(&ws[WS_LOSS], lsum);
}

// ---------- kernel 3: dw scatter + finalize, fused ----------
__global__ __launch_bounds__(512) void k_dwf(
    const u16* __restrict__ z, const float* __restrict__ idxf,
    const u16* __restrict__ cs, const u16* __restrict__ ema,
    float* __restrict__ ws, float* __restrict__ out,
    int K, int N, long long offLoss, long long outSize, float lossScale)
{
    __shared__ int   queue[2048];
    __shared__ int   qcnt;
    __shared__ float cnt[8];
    __shared__ float red[8][512];
    __shared__ float red2[512];

    const int KB = K >> 8;
    const int base = blockIdx.x * KB;
    const int t = threadIdx.x;
    const int w = t >> 6, lane = t & 63;
    const int* wsi = (const int*)ws;
    const int fz = wsi[WS_FZ], fcs = wsi[WS_FCS], fema = wsi[WS_FEMA];

    if (t == 0) qcnt = 0;
    if (t < 8) cnt[t] = 0.0f;
    float acc[8] = {0.f, 0.f, 0.f, 0.f, 0.f, 0.f, 0.f, 0.f};
    __syncthreads();

    const int nseg = (N + 2047) / 2048;
    for (int s = 0; s < nseg; ++s) {
        int i4 = s * 512 + t;
        if (i4 * 4 < N) {
            f4 v = ((const f4*)idxf)[i4];
            #pragma unroll
            for (int j = 0; j < 4; ++j) {
                int k = (int)v[j];
                if (k >= base && k < base + KB) {
                    int qi = atomicAdd(&qcnt, 1);
                    queue[qi] = ((i4 * 4 + j) << 3) | (k - base);
                    atomicAdd(&cnt[k - base], 1.0f);
                }
            }
        }
        __syncthreads();
        const int n = qcnt;
        for (int ent = w; ent < n; ent += 8) {
            int q = queue[ent];
            int p = q >> 3, kl = q & 7;
            float v = fz ? ((const float*)z)[(size_t)p * 64 + lane]
                         : b2f(z[(size_t)p * 64 + lane]);
            #pragma unroll
            for (int c = 0; c < 8; ++c) acc[c] += (c == kl) ? v : 0.0f;
        }
        __syncthreads();
        if (t == 0) qcnt = 0;
        __syncthreads();
    }

    #pragma unroll
    for (int c = 0; c < 8; ++c)
        if (c < KB) red[w][c * 64 + lane] = acc[c];

    float partial = 0.f;
    for (int k0 = 0; k0 < K; k0 += 512) {
        int kk = k0 + t;
        if (kk < K) partial += fcs ? ((const float*)cs)[kk] : b2f(cs[kk]);
    }
    red2[t] = partial;
    __syncthreads();
    for (int s = 256; s; s >>= 1) {
        if (t < s) red2[t] += red2[t + s];
        __syncthreads();
    }
    const float n = 0.99f * red2[0] + 0.01f * (float)N;
    const float keps = (float)K * 1e-5f;

    const long long offEmb = offLoss + 1;
    const long long offCl  = offEmb + (long long)K * 64;
    const long long offEma = offCl + K;

    if (t < KB * 64) {
        int kl = t >> 6, d = t & 63;
        int kk = base + kl;
        float dw = 0.f;
        #pragma unroll
        for (int ww = 0; ww < 8; ++ww) dw += red[ww][kl * 64 + d];
        float c = (fcs ? ((const float*)cs)[kk] : b2f(cs[kk])) * 0.99f + cnt[kl] * 0.01f;
        float sm = (c + 1e-5f) / (n + keps) * n;
        long long i = (long long)kk * 64 + d;
        float ev = fema ? ((const float*)ema)[i] : b2f(ema[i]);
        float ne = ev * 0.99f + dw * 0.01f;
        if (offEma + i < outSize) out[offEma + i] = ne;
        if (offEmb + i < outSize) out[offEmb + i] = ne / sm;
        if (d == 0 && offCl + kk < outSize) out[offCl + kk] = sm;
    }
    if (blockIdx.x == 0 && t == 0 && offLoss < outSize)
        out[offLoss] = 0.25f * (ws[WS_LOSS] * lossScale);
}

extern "C" void kernel_launch(void* const* d_in, const int* in_sizes, int n_in,
                              void* d_out, int out_size, void* d_ws, size_t ws_size,
                              hipStream_t stream) {
    long long sz[4] = {0, 0, 0, 0};
    for (int i = 0; i < n_in && i < 4; ++i) sz[i] = in_sizes[i];
    int icl = 0, iz = 0;
    for (int i = 1; i < 4; ++i) { if (sz[i] < sz[icl]) icl = i; if (sz[i] > sz[iz]) iz = i; }
    int ip[2], np = 0;
    for (int i = 0; i < 4; ++i) if (i != icl && i != iz && np < 2) ip[np++] = i;
    long long K = sz[icl], KD = (np == 2) ? sz[ip[0]] : 0;
    int derivOK = (n_in == 4 && np == 2 && icl != iz && sz[ip[0]] == sz[ip[1]] &&
                   K > 0 && KD % K == 0);
    long long D = derivOK ? KD / K : 64;
    long long N = (derivOK && D > 0 && sz[iz] % D == 0) ? sz[iz] / D : 32768;
    int ie, iema;
    if (!derivOK) { iz = 0; ie = 1; icl = 2; iema = 3; N = 32768; K = 1024; D = 64; }
    else if (icl > ip[0] && icl < ip[1]) { ie = ip[0]; iema = ip[1]; }  // dict order
    else { iema = ip[0]; ie = ip[1]; }                                  // sorted order

    int fastOK = (D == 64) && (N % 1024 == 0) && (K % 256 == 0) &&
                 (K >= 512) && (K <= 2048);
    if (!fastOK) { N = 32768; K = 1024; }

    long long offIdx = N * 64, offLoss = offIdx + N;

    float* out = (float*)d_out;
    float* ws = (float*)d_ws;
    float* esqp = ((long long)ws_size >= (8 + K) * 4) ? (ws + 8)
                 : (out + offLoss + 1 + K * 64);

    const u16* z   = (const u16*)d_in[iz];
    const u16* e   = (const u16*)d_in[ie];
    const u16* cs  = (const u16*)d_in[icl];
    const u16* ema = (const u16*)d_in[iema];

    float lossScale = (float)(1.0 / (double)(N * 64));

    k_init<<<(int)((K + 255) / 256), 256, 0, stream>>>(z, e, cs, ema, ws, esqp, (int)K);
    k_main<<<(int)(N / 128), 512, 0, stream>>>(z, e, esqp, ws, out,
                                               (int)K, (int)offIdx, (long long)out_size);
    k_dwf<<<256, 512, 0, stream>>>(z, out + offIdx, cs, ema, ws, out,
                                   (int)K, (int)N, offLoss,
                                   (long long)out_size, lossScale);
}

// Round 19
// 209.840 us; speedup vs baseline: 1.0080x; 1.0080x over previous
//
#include <hip/hip_runtime.h>

// QuantizerEMA (B,H,W,D,K)=(32,32,32,64,1024), N=32768. fp32 in / fp32 out.
// Output float32 chunks: QV[B,D,H,W] (N*64), IDX (N), loss, EMB[K,64], CL[K],
// EMA[K,64]. R19 = exact revert to R17 (best measured: 209.8us total, k_main
// 94us). R18's float2/v_pk_fma_f32 experiment regressed 15% (operand-forming
// shuffles outweighed packing) and is dropped. Argmin numerics bitwise as
// R9-R17 (pairwise-8 norms, sequential-k FMA chains, dist=(z2+e2)-2*acc,
// first-index ties).

typedef unsigned short u16;
typedef u16 us8 __attribute__((ext_vector_type(8)));
typedef float f4 __attribute__((ext_vector_type(4)));

#define WS_FZ    0
#define WS_FE    1
#define WS_FCS   2
#define WS_FEMA  3
#define WS_LOSS  4

__device__ __forceinline__ float b2f(u16 u) {
    union { unsigned int i; float f; } x; x.i = ((unsigned int)u) << 16; return x.f;
}
__device__ __forceinline__ int swzE(int d, int c) {
    return d * 64 + (c ^ ((((d) >> 2) & 7) << 2));
}
__device__ __forceinline__ int swzZ(int d, int c) {
    int cb = (c >> 2) ^ (c >> 5);
    int cc = ((cb & 31) << 2) | (c & 3);
    return d * 128 + (cc ^ ((((d) >> 2) & 7) << 2));
}

// ---------- kernel 1: dtype detect + e^2 table ----------
__global__ __launch_bounds__(256) void k_init(
    const u16* z, const u16* e, const u16* cs, const u16* ema,
    float* __restrict__ ws, float* __restrict__ esqp, int K)
{
    __shared__ int flg[4];
    const int w = threadIdx.x >> 6, l = threadIdx.x & 63;
    const u16* p = (w == 0) ? z : (w == 1) ? e : (w == 2) ? cs : ema;
    int cnt = 0;
    #pragma unroll
    for (int t = 0; t < 4; ++t) {
        unsigned hb = (p[(l * 4 + t) * 2] >> 8) & 0x7F;
        cnt += (hb >= 0x3A && hb <= 0x41) ? 1 : 0;
    }
    #pragma unroll
    for (int off = 32; off; off >>= 1) cnt += __shfl_down(cnt, off);
    if (l == 0) flg[w] = (cnt < 128) ? 1 : 0;
    __syncthreads();
    if (blockIdx.x == 0) {
        if (threadIdx.x < 4) ((int*)ws)[threadIdx.x] = flg[threadIdx.x];
        if (threadIdx.x == 4) ws[WS_LOSS] = 0.0f;
    }
    const int fe = flg[1];
    const int code = blockIdx.x * 256 + threadIdx.x;
    if (code < K) {
        float r[8];
        if (fe) {
            const float* ep = (const float*)e + (size_t)code * 64;
            #pragma unroll
            for (int j = 0; j < 8; ++j) { float v = ep[j]; float p2 = v * v;
                asm volatile("" : "+v"(p2)); r[j] = p2; }
            #pragma unroll
            for (int t = 1; t < 8; ++t)
                #pragma unroll
                for (int j = 0; j < 8; ++j) { float v = ep[8 * t + j]; float p2 = v * v;
                    asm volatile("" : "+v"(p2)); r[j] += p2; }
        } else {
            const u16* ep = e + (size_t)code * 64;
            #pragma unroll
            for (int j = 0; j < 8; ++j) { float v = b2f(ep[j]); float p2 = v * v;
                asm volatile("" : "+v"(p2)); r[j] = p2; }
            #pragma unroll
            for (int t = 1; t < 8; ++t)
                #pragma unroll
                for (int j = 0; j < 8; ++j) { float v = b2f(ep[8 * t + j]); float p2 = v * v;
                    asm volatile("" : "+v"(p2)); r[j] += p2; }
        }
        esqp[code] = ((r[0] + r[1]) + (r[2] + r[3])) + ((r[4] + r[5]) + (r[6] + r[7]));
    }
}

// ---------- kernel 2: distances + argmin + QV/loss epilogue ----------
// 256 blocks x 512 thr; 128 points/block; 4 wave-groups each scan a quarter
// of the codebook with a private e-tile; 8x8 register tile.
__global__ __launch_bounds__(512, 2) void k_main(
    const u16* __restrict__ z, const u16* __restrict__ e,
    const float* __restrict__ esqp,
    float* __restrict__ ws, float* __restrict__ out,
    int K, int offIdx, long long outSize)
{
    __shared__ __align__(16) float z_t[64 * 128];       // 32 KB, swzZ
    __shared__ __align__(16) float e_t[4 * 64 * 64];    // 64 KB, swzE per group
    __shared__ float esq_l[2048];                       // 8 KB (K <= 2048)
    __shared__ float z2_l[128];
    __shared__ int   idx_l[128];

    const int tid = threadIdx.x;
    const int cg  = tid >> 7;
    const int lt  = tid & 127;
    const int mtg = lt & 15;
    const int ktg = lt >> 4;
    const int pbase = blockIdx.x * 128;
    const int* wsi = (const int*)ws;
    const int fz = wsi[WS_FZ];
    const int fe = wsi[WS_FE];
    const int kchunks = K >> 6;
    const int h = kchunks >> 2;

    // stage esq to LDS (read-only afterwards)
    for (int i = tid; i < K; i += 512) esq_l[i] = esqp[i];

    // ---- stage z tile (128 pts x 64 d), swizzled ----
    if (fz) {
        const f4* z4 = (const f4*)((const float*)z + (size_t)pbase * 64);
        for (int i = tid; i < 2048; i += 512) {
            f4 v = z4[i];
            int m = i >> 4, d4 = (i & 15) * 4;
            z_t[swzZ(d4 + 0, m)] = v[0];
            z_t[swzZ(d4 + 1, m)] = v[1];
            z_t[swzZ(d4 + 2, m)] = v[2];
            z_t[swzZ(d4 + 3, m)] = v[3];
        }
    } else {
        const us8* z8 = (const us8*)(z + (size_t)pbase * 64);
        for (int i = tid; i < 1024; i += 512) {
            us8 v = z8[i];
            int m = i >> 3, d8 = (i & 7) * 8;
            #pragma unroll
            for (int t = 0; t < 8; ++t) z_t[swzZ(d8 + t, m)] = b2f(v[t]);
        }
    }
    __syncthreads();
    if (tid < 128) {   // ||z||^2, np pairwise-8 order, anti-FMA barriers
        float r[8];
        #pragma unroll
        for (int j = 0; j < 8; ++j) {
            float v = z_t[swzZ(j, tid)]; float p = v * v;
            asm volatile("" : "+v"(p)); r[j] = p;
        }
        #pragma unroll
        for (int t = 1; t < 8; ++t)
            #pragma unroll
            for (int j = 0; j < 8; ++j) {
                float v = z_t[swzZ(8 * t + j, tid)]; float p = v * v;
                asm volatile("" : "+v"(p)); r[j] += p;
            }
        z2_l[tid] = ((r[0] + r[1]) + (r[2] + r[3])) + ((r[4] + r[5]) + (r[6] + r[7]));
    }

    float bestd[8] = {INFINITY, INFINITY, INFINITY, INFINITY,
                      INFINITY, INFINITY, INFINITY, INFINITY};
    int   besti[8] = {0, 0, 0, 0, 0, 0, 0, 0};
    float* et = e_t + cg * 4096;

    f4  fb[8];
    us8 hb[4];
    {
        int kc0 = cg * h;
        if (fe) {
            const f4* e4 = (const f4*)((const float*)e + (size_t)kc0 * 4096);
            #pragma unroll
            for (int t = 0; t < 8; ++t) fb[t] = e4[lt + 128 * t];
        } else {
            const us8* e8 = (const us8*)(e + (size_t)kc0 * 4096);
            #pragma unroll
            for (int t = 0; t < 4; ++t) hb[t] = e8[lt + 128 * t];
        }
    }

    for (int c = 0; c < h; ++c) {
        const int kc = cg * h + c;
        if (fe) {
            #pragma unroll
            for (int t = 0; t < 8; ++t) {
                int i = lt + 128 * t;
                int kl = i >> 4, d4 = (i & 15) * 4;
                et[swzE(d4 + 0, kl)] = fb[t][0];
                et[swzE(d4 + 1, kl)] = fb[t][1];
                et[swzE(d4 + 2, kl)] = fb[t][2];
                et[swzE(d4 + 3, kl)] = fb[t][3];
            }
        } else {
            #pragma unroll
            for (int t = 0; t < 4; ++t) {
                int i = lt + 128 * t;
                int kl = i >> 3, d8 = (i & 7) * 8;
                #pragma unroll
                for (int s = 0; s < 8; ++s) et[swzE(d8 + s, kl)] = b2f(hb[t][s]);
            }
        }
        if (c + 1 < h) {   // prefetch next chunk during compute
            if (fe) {
                const f4* e4 = (const f4*)((const float*)e + (size_t)(kc + 1) * 4096);
                #pragma unroll
                for (int t = 0; t < 8; ++t) fb[t] = e4[lt + 128 * t];
            } else {
                const us8* e8 = (const us8*)(e + (size_t)(kc + 1) * 4096);
                #pragma unroll
                for (int t = 0; t < 4; ++t) hb[t] = e8[lt + 128 * t];
            }
        }
        __syncthreads();   // e_t ready (and z2_l/esq_l on first pass)

        float acc[8][8] = {};
        // 8x8 tile; each acc[a][b] is a sequential d=0..63 FMA chain (bitwise).
        // NO unroll pragma (R16 spill); NO f2 packing (R18 regression).
        for (int d0 = 0; d0 < 64; d0 += 4) {
            f4 za[4], zb[4], ea[4], eb[4];
            #pragma unroll
            for (int j = 0; j < 4; ++j) {
                int d = d0 + j;
                za[j] = *(const f4*)&z_t[swzZ(d, mtg * 8)];
                zb[j] = *(const f4*)&z_t[swzZ(d, mtg * 8 + 4)];
                ea[j] = *(const f4*)&et[swzE(d, ktg * 8)];
                eb[j] = *(const f4*)&et[swzE(d, ktg * 8 + 4)];
            }
            #pragma unroll
            for (int j = 0; j < 4; ++j) {
                #pragma unroll
                for (int a = 0; a < 4; ++a)
                    #pragma unroll
                    for (int b = 0; b < 4; ++b) {
                        acc[a][b]         += za[j][a] * ea[j][b];
                        acc[a][b + 4]     += za[j][a] * eb[j][b];
                        acc[a + 4][b]     += zb[j][a] * ea[j][b];
                        acc[a + 4][b + 4] += zb[j][a] * eb[j][b];
                    }
            }
        }
        __syncthreads();   // readers done -> next staging write safe

        #pragma unroll
        for (int a = 0; a < 8; ++a) {
            float z2 = z2_l[mtg * 8 + a];
            #pragma unroll
            for (int b = 0; b < 8; ++b) {
                float e2 = esq_l[kc * 64 + ktg * 8 + b];
                float dist = (z2 + e2) - 2.0f * acc[a][b];
                int kg = kc * 64 + ktg * 8 + b;
                if (dist < bestd[a]) { bestd[a] = dist; besti[a] = kg; }  // first-wins
            }
        }
    }

    // ---- argmin merge: 32 slots/point, stride 33 (bank-spread), overlay e_t ----
    float* red_d = e_t;                  // 128*33 floats
    int*   red_i = (int*)(e_t + 4224);   // 128*33 ints
    #pragma unroll
    for (int a = 0; a < 8; ++a) {
        red_d[(mtg * 8 + a) * 33 + (cg * 8 + ktg)] = bestd[a];
        red_i[(mtg * 8 + a) * 33 + (cg * 8 + ktg)] = besti[a];
    }
    __syncthreads();

    if (tid < 128) {
        float bd = red_d[tid * 33]; int bi = red_i[tid * 33];
        #pragma unroll
        for (int t = 1; t < 32; ++t) {
            float dv = red_d[tid * 33 + t]; int iv = red_i[tid * 33 + t];
            if (dv < bd || (dv == bd && iv < bi)) { bd = dv; bi = iv; }
        }
        idx_l[tid] = bi;
        long long oi = (long long)offIdx + pbase + tid;
        if (oi < outSize) out[oi] = (float)bi;
    }
    __syncthreads();

    // ---- epilogue: QV transposed store + loss ----
    const int m = tid & 127;
    const int w = tid >> 7;
    const int p = pbase + m;
    const int b = p >> 10;
    const int hw = p & 1023;
    const int kidx = idx_l[m];
    float lsum = 0.f;
    #pragma unroll
    for (int dd = 0; dd < 16; ++dd) {
        int d = w + 4 * dd;
        float zv = z_t[swzZ(d, m)];
        float q  = fe ? ((const float*)e)[(size_t)kidx * 64 + d]
                      : b2f(e[(size_t)kidx * 64 + d]);
        float df = zv - q;
        lsum += df * df;
        float qs = zv + (q - zv);
        long long qi = (long long)b * 65536 + d * 1024 + hw;
        if (qi < outSize) out[qi] = qs;
    }
    #pragma unroll
    for (int off = 32; off; off >>= 1) lsum += __shfl_down(lsum, off);
    if ((tid & 63) == 0) atomicAdd(&ws[WS_LOSS], lsum);
}

// ---------- kernel 3: dw scatter + finalize, fused ----------
__global__ __launch_bounds__(512) void k_dwf(
    const u16* __restrict__ z, const float* __restrict__ idxf,
    const u16* __restrict__ cs, const u16* __restrict__ ema,
    float* __restrict__ ws, float* __restrict__ out,
    int K, int N, long long offLoss, long long outSize, float lossScale)
{
    __shared__ int   queue[2048];
    __shared__ int   qcnt;
    __shared__ float cnt[8];
    __shared__ float red[8][512];
    __shared__ float red2[512];

    const int KB = K >> 8;
    const int base = blockIdx.x * KB;
    const int t = threadIdx.x;
    const int w = t >> 6, lane = t & 63;
    const int* wsi = (const int*)ws;
    const int fz = wsi[WS_FZ], fcs = wsi[WS_FCS], fema = wsi[WS_FEMA];

    if (t == 0) qcnt = 0;
    if (t < 8) cnt[t] = 0.0f;
    float acc[8] = {0.f, 0.f, 0.f, 0.f, 0.f, 0.f, 0.f, 0.f};
    __syncthreads();

    const int nseg = (N + 2047) / 2048;
    for (int s = 0; s < nseg; ++s) {
        int i4 = s * 512 + t;
        if (i4 * 4 < N) {
            f4 v = ((const f4*)idxf)[i4];
            #pragma unroll
            for (int j = 0; j < 4; ++j) {
                int k = (int)v[j];
                if (k >= base && k < base + KB) {
                    int qi = atomicAdd(&qcnt, 1);
                    queue[qi] = ((i4 * 4 + j) << 3) | (k - base);
                    atomicAdd(&cnt[k - base], 1.0f);
                }
            }
        }
        __syncthreads();
        const int n = qcnt;
        for (int ent = w; ent < n; ent += 8) {
            int q = queue[ent];
            int p = q >> 3, kl = q & 7;
            float v = fz ? ((const float*)z)[(size_t)p * 64 + lane]
                         : b2f(z[(size_t)p * 64 + lane]);
            #pragma unroll
            for (int c = 0; c < 8; ++c) acc[c] += (c == kl) ? v : 0.0f;
        }
        __syncthreads();
        if (t == 0) qcnt = 0;
        __syncthreads();
    }

    #pragma unroll
    for (int c = 0; c < 8; ++c)
        if (c < KB) red[w][c * 64 + lane] = acc[c];

    float partial = 0.f;
    for (int k0 = 0; k0 < K; k0 += 512) {
        int kk = k0 + t;
        if (kk < K) partial += fcs ? ((const float*)cs)[kk] : b2f(cs[kk]);
    }
    red2[t] = partial;
    __syncthreads();
    for (int s = 256; s; s >>= 1) {
        if (t < s) red2[t] += red2[t + s];
        __syncthreads();
    }
    const float n = 0.99f * red2[0] + 0.01f * (float)N;
    const float keps = (float)K * 1e-5f;

    const long long offEmb = offLoss + 1;
    const long long offCl  = offEmb + (long long)K * 64;
    const long long offEma = offCl + K;

    if (t < KB * 64) {
        int kl = t >> 6, d = t & 63;
        int kk = base + kl;
        float dw = 0.f;
        #pragma unroll
        for (int ww = 0; ww < 8; ++ww) dw += red[ww][kl * 64 + d];
        float c = (fcs ? ((const float*)cs)[kk] : b2f(cs[kk])) * 0.99f + cnt[kl] * 0.01f;
        float sm = (c + 1e-5f) / (n + keps) * n;
        long long i = (long long)kk * 64 + d;
        float ev = fema ? ((const float*)ema)[i] : b2f(ema[i]);
        float ne = ev * 0.99f + dw * 0.01f;
        if (offEma + i < outSize) out[offEma + i] = ne;
        if (offEmb + i < outSize) out[offEmb + i] = ne / sm;
        if (d == 0 && offCl + kk < outSize) out[offCl + kk] = sm;
    }
    if (blockIdx.x == 0 && t == 0 && offLoss < outSize)
        out[offLoss] = 0.25f * (ws[WS_LOSS] * lossScale);
}

extern "C" void kernel_launch(void* const* d_in, const int* in_sizes, int n_in,
                              void* d_out, int out_size, void* d_ws, size_t ws_size,
                              hipStream_t stream) {
    long long sz[4] = {0, 0, 0, 0};
    for (int i = 0; i < n_in && i < 4; ++i) sz[i] = in_sizes[i];
    int icl = 0, iz = 0;
    for (int i = 1; i < 4; ++i) { if (sz[i] < sz[icl]) icl = i; if (sz[i] > sz[iz]) iz = i; }
    int ip[2], np = 0;
    for (int i = 0; i < 4; ++i) if (i != icl && i != iz && np < 2) ip[np++] = i;
    long long K = sz[icl], KD = (np == 2) ? sz[ip[0]] : 0;
    int derivOK = (n_in == 4 && np == 2 && icl != iz && sz[ip[0]] == sz[ip[1]] &&
                   K > 0 && KD % K == 0);
    long long D = derivOK ? KD / K : 64;
    long long N = (derivOK && D > 0 && sz[iz] % D == 0) ? sz[iz] / D : 32768;
    int ie, iema;
    if (!derivOK) { iz = 0; ie = 1; icl = 2; iema = 3; N = 32768; K = 1024; D = 64; }
    else if (icl > ip[0] && icl < ip[1]) { ie = ip[0]; iema = ip[1]; }  // dict order
    else { iema = ip[0]; ie = ip[1]; }                                  // sorted order

    int fastOK = (D == 64) && (N % 1024 == 0) && (K % 256 == 0) &&
                 (K >= 512) && (K <= 2048);
    if (!fastOK) { N = 32768; K = 1024; }

    long long offIdx = N * 64, offLoss = offIdx + N;

    float* out = (float*)d_out;
    float* ws = (float*)d_ws;
    float* esqp = ((long long)ws_size >= (8 + K) * 4) ? (ws + 8)
                 : (out + offLoss + 1 + K * 64);

    const u16* z   = (const u16*)d_in[iz];
    const u16* e   = (const u16*)d_in[ie];
    const u16* cs  = (const u16*)d_in[icl];
    const u16* ema = (const u16*)d_in[iema];

    float lossScale = (float)(1.0 / (double)(N * 64));

    k_init<<<(int)((K + 255) / 256), 256, 0, stream>>>(z, e, cs, ema, ws, esqp, (int)K);
    k_main<<<(int)(N / 128), 512, 0, stream>>>(z, e, esqp, ws, out,
                                               (int)K, (int)offIdx, (long long)out_size);
    k_dwf<<<256, 512, 0, stream>>>(z, out + offIdx, cs, ema, ws, out,
                                   (int)K, (int)N, offLoss,
                                   (long long)out_size, lossScale);
}